// Round 1
// baseline (3005.822 us; speedup 1.0000x reference)
//
#include <hip/hip_runtime.h>
#include <math.h>

#define N_ITERS 7
#define HF 10      // GRU hidden size (node features)
#define NIN 9      // node inputs
#define EF 11      // edge features / message size
#define MSG 96
#define CIN (2*HF + EF)   // 31
#define GIN (EF + NIN)    // 20

// Dense layer: y[OUT] = act(W[OUT,IN] @ x[IN] + b[OUT]); W row-major, uniform
// (weights indexed by compile-time constants -> scalar loads feeding v_fmac).
template<int IN, int OUT, bool RELU>
__device__ __forceinline__ void dense(const float* __restrict__ x, float* __restrict__ y,
                                      const float* __restrict__ W, const float* __restrict__ b)
{
#pragma unroll
    for (int j0 = 0; j0 < OUT; j0 += 16) {
        float acc[16];
#pragma unroll
        for (int jj = 0; jj < 16; ++jj) acc[jj] = b[j0 + jj];
#pragma unroll
        for (int k = 0; k < IN; ++k) {
            const float a = x[k];
#pragma unroll
            for (int jj = 0; jj < 16; ++jj)
                acc[jj] = fmaf(a, W[(j0 + jj) * IN + k], acc[jj]);
        }
#pragma unroll
        for (int jj = 0; jj < 16; ++jj)
            y[j0 + jj] = RELU ? fmaxf(acc[jj], 0.0f) : acc[jj];
    }
}

__global__ __launch_bounds__(256) void edge_mlp_kernel(
    const float* __restrict__ h, const float* __restrict__ edge_attr,
    const float* __restrict__ W1, const float* __restrict__ b1,
    const float* __restrict__ W2, const float* __restrict__ b2,
    const float* __restrict__ W3, const float* __restrict__ b3,
    const float* __restrict__ W4, const float* __restrict__ b4,
    const int* __restrict__ src, const int* __restrict__ dst,
    float* __restrict__ agg, int E)
{
    const int e = blockIdx.x * blockDim.x + threadIdx.x;
    if (e >= E) return;
    const int s = src[e];
    const int d = dst[e];

    float in[CIN];
#pragma unroll
    for (int k = 0; k < HF; ++k) in[k] = h[s * HF + k];
#pragma unroll
    for (int k = 0; k < HF; ++k) in[HF + k] = h[d * HF + k];
#pragma unroll
    for (int k = 0; k < EF; ++k) in[2 * HF + k] = edge_attr[(size_t)e * EF + k];

    float mA[MSG];
    float mB[MSG];
    dense<CIN, MSG, true>(in, mA, W1, b1);
    dense<MSG, MSG, true>(mA, mB, W2, b2);
    dense<MSG, MSG, true>(mB, mA, W3, b3);

    // layer 4: [MSG] -> [EF], no activation, scatter-add to agg[dst]
    float* aggd = agg + (size_t)d * EF;
#pragma unroll
    for (int j = 0; j < EF; ++j) {
        float acc = b4[j];
#pragma unroll
        for (int k = 0; k < MSG; ++k)
            acc = fmaf(mA[k], W4[j * MSG + k], acc);
        atomicAdd(&aggd[j], acc);
    }
}

__global__ __launch_bounds__(256) void gru_node_kernel(
    const float* __restrict__ node_inputs,
    float* __restrict__ h, float* __restrict__ agg,
    const float* __restrict__ wih, const float* __restrict__ whh,
    const float* __restrict__ bih, const float* __restrict__ bhh,
    const float* __restrict__ fw, const float* __restrict__ fb,
    float* __restrict__ out_t, int N)
{
    const int n = blockIdx.x * blockDim.x + threadIdx.x;
    if (n >= N) return;

    float x[GIN];
#pragma unroll
    for (int k = 0; k < EF; ++k) {
        x[k] = agg[(size_t)n * EF + k];
        agg[(size_t)n * EF + k] = 0.0f;   // re-zero for next iteration's atomics
    }
#pragma unroll
    for (int k = 0; k < NIN; ++k) x[EF + k] = node_inputs[(size_t)n * NIN + k];

    float hv[HF];
#pragma unroll
    for (int k = 0; k < HF; ++k) hv[k] = h[(size_t)n * HF + k];

    float gi[3 * HF];
    float gh[3 * HF];
#pragma unroll
    for (int j = 0; j < 3 * HF; ++j) {
        float a = bih[j];
#pragma unroll
        for (int k = 0; k < GIN; ++k) a = fmaf(x[k], wih[j * GIN + k], a);
        gi[j] = a;
        float g = bhh[j];
#pragma unroll
        for (int k = 0; k < HF; ++k) g = fmaf(hv[k], whh[j * HF + k], g);
        gh[j] = g;
    }

    float hn[HF];
#pragma unroll
    for (int k = 0; k < HF; ++k) {
        const float r = 1.0f / (1.0f + __expf(-(gi[k] + gh[k])));
        const float z = 1.0f / (1.0f + __expf(-(gi[HF + k] + gh[HF + k])));
        const float nn = tanhf(gi[2 * HF + k] + r * gh[2 * HF + k]);
        hn[k] = (1.0f - z) * nn + z * hv[k];
    }
#pragma unroll
    for (int k = 0; k < HF; ++k) h[(size_t)n * HF + k] = hn[k];

    float l0 = fb[0], l1 = fb[1];
#pragma unroll
    for (int k = 0; k < HF; ++k) {
        l0 = fmaf(hn[k], fw[k], l0);
        l1 = fmaf(hn[k], fw[HF + k], l1);
    }
    out_t[(size_t)n * 2 + 0] = l0;
    out_t[(size_t)n * 2 + 1] = l1;
}

extern "C" void kernel_launch(void* const* d_in, const int* in_sizes, int n_in,
                              void* d_out, int out_size, void* d_ws, size_t ws_size,
                              hipStream_t stream) {
    const float* node_inputs = (const float*)d_in[0];
    const float* edge_attr   = (const float*)d_in[1];
    const float* W1 = (const float*)d_in[2];
    const float* b1 = (const float*)d_in[3];
    const float* W2 = (const float*)d_in[4];
    const float* b2 = (const float*)d_in[5];
    const float* W3 = (const float*)d_in[6];
    const float* b3 = (const float*)d_in[7];
    const float* W4 = (const float*)d_in[8];
    const float* b4 = (const float*)d_in[9];
    const float* gru_wih = (const float*)d_in[10];
    const float* gru_whh = (const float*)d_in[11];
    const float* gru_bih = (const float*)d_in[12];
    const float* gru_bhh = (const float*)d_in[13];
    const float* fin_w   = (const float*)d_in[14];
    const float* fin_b   = (const float*)d_in[15];
    const int* src_ids = (const int*)d_in[16];
    const int* dst_ids = (const int*)d_in[17];

    const int N = in_sizes[0] / NIN;
    const int E = in_sizes[1] / EF;

    float* h   = (float*)d_ws;            // N*HF floats
    float* agg = h + (size_t)N * HF;      // N*EF floats

    // zero h0 and agg once; gru_node_kernel re-zeros agg each iteration
    hipMemsetAsync(d_ws, 0, (size_t)N * (HF + EF) * sizeof(float), stream);

    float* out = (float*)d_out;
    const int edge_blocks = (E + 255) / 256;
    const int node_blocks = (N + 255) / 256;

    for (int t = 0; t < N_ITERS; ++t) {
        edge_mlp_kernel<<<edge_blocks, 256, 0, stream>>>(
            h, edge_attr, W1, b1, W2, b2, W3, b3, W4, b4,
            src_ids, dst_ids, agg, E);
        gru_node_kernel<<<node_blocks, 256, 0, stream>>>(
            node_inputs, h, agg, gru_wih, gru_whh, gru_bih, gru_bhh,
            fin_w, fin_b, out + (size_t)t * N * 2, N);
    }
}

// Round 2
// 959.203 us; speedup vs baseline: 3.1337x; 3.1337x over previous
//
#include <hip/hip_runtime.h>
#include <math.h>

typedef _Float16 f16;
typedef f16 f16x8 __attribute__((ext_vector_type(8)));
typedef f16 f16x4 __attribute__((ext_vector_type(4)));
typedef float f32x4 __attribute__((ext_vector_type(4)));

#define N_ITERS 7
#define HF 10      // GRU hidden size
#define NIN 9      // node inputs
#define EF 11      // edge features / message size
#define MSG 96
#define GIN (EF + NIN)

#define S1 40      // f16 row stride for W1 (K=32 padded to 40 for bank spread)
#define S2 104     // f16 row stride for W2/W3/W4 and activation LDS (96 -> 104)
#define G  4       // 16-edge groups per wave

// ---------------- weight preconversion (once per launch) ----------------
__global__ __launch_bounds__(256) void convert_weights(
    const float* __restrict__ W1, const float* __restrict__ W2,
    const float* __restrict__ W3, const float* __restrict__ W4,
    f16* __restrict__ wf)
{
    f16* wf1 = wf;
    f16* wf2 = wf1 + 96 * S1;
    f16* wf3 = wf2 + 96 * S2;
    f16* wf4 = wf3 + 96 * S2;
    const int tid = blockIdx.x * 256 + threadIdx.x;
    const int nt = gridDim.x * 256;
    for (int i = tid; i < 96 * S1; i += nt) {
        int m = i / S1, k = i % S1;
        wf1[i] = (k < 31) ? (f16)W1[m * 31 + k] : (f16)0.f;
    }
    for (int i = tid; i < 96 * S2; i += nt) {
        int m = i / S2, k = i % S2;
        wf2[i] = (k < 96) ? (f16)W2[m * 96 + k] : (f16)0.f;
        wf3[i] = (k < 96) ? (f16)W3[m * 96 + k] : (f16)0.f;
    }
    for (int i = tid; i < 16 * S2; i += nt) {
        int m = i / S2, k = i % S2;
        wf4[i] = (m < 11 && k < 96) ? (f16)W4[m * 96 + k] : (f16)0.f;
    }
}

// relu + cvt to f16x4 + 8B LDS store
__device__ __forceinline__ void store_relu4(f16* p, f32x4 c) {
    f16x4 o;
#pragma unroll
    for (int r = 0; r < 4; ++r) o[r] = (f16)fmaxf(c[r], 0.0f);
    *(f16x4*)p = o;
}

// ---------------- edge MLP via MFMA ----------------
// One wave processes G groups of 16 edges. Weights = A operand (m = out
// neuron), activations = B operand (n = edge). D is col(edge)-per-lane,
// written to wave-private LDS act[n][k] so the next layer reads B-frags
// with ds_read_b128. No barriers needed (each lane touches only row n).
__global__ __launch_bounds__(256, 2) void edge_mlp_mfma(
    const float* __restrict__ h, const float* __restrict__ ea,
    const f16* __restrict__ wf,
    const float* __restrict__ b1, const float* __restrict__ b2,
    const float* __restrict__ b3, const float* __restrict__ b4,
    const int* __restrict__ src, const int* __restrict__ dst,
    float* __restrict__ agg, int E)
{
    const f16* wf1 = wf;
    const f16* wf2 = wf1 + 96 * S1;
    const f16* wf3 = wf2 + 96 * S2;
    const f16* wf4 = wf3 + 96 * S2;

    __shared__ f16 act[4][G][16][S2];   // 53,248 B

    const int wave = threadIdx.x >> 6;
    const int lane = threadIdx.x & 63;
    const int n = lane & 15;       // edge-in-group (B col / C col)
    const int q = lane >> 4;       // quad

    const int ebase = blockIdx.x * 256 + wave * (G * 16);

    // ---------------- layer 1: [31] -> [96], relu ----------------
    {
        f16x8 a[6];
#pragma unroll
        for (int t = 0; t < 6; ++t)
            a[t] = *(const f16x8*)(wf1 + (t * 16 + n) * S1 + 8 * q);
        f32x4 bias[6];
#pragma unroll
        for (int t = 0; t < 6; ++t)
            bias[t] = *(const f32x4*)(b1 + t * 16 + 4 * q);
#pragma unroll
        for (int g = 0; g < G; ++g) {
            const int eg = ebase + g * 16 + n;
            const bool valid = eg < E;
            const int e = valid ? eg : 0;
            const int s = src[e], d = dst[e];
            f16x8 bf;
#pragma unroll
            for (int j = 0; j < 8; ++j) {
                const int k = 8 * q + j;
                float v;
                if (k < 10)      v = h[s * HF + k];
                else if (k < 20) v = h[d * HF + (k - 10)];
                else if (k < 31) v = ea[(size_t)e * EF + (k - 20)];
                else             v = 0.0f;
                bf[j] = (f16)v;
            }
#pragma unroll
            for (int t = 0; t < 6; ++t) {
                f32x4 c = __builtin_amdgcn_mfma_f32_16x16x32_f16(a[t], bf, bias[t], 0, 0, 0);
                store_relu4(&act[wave][g][n][t * 16 + 4 * q], c);
            }
        }
    }

    // ---------------- layers 2,3: [96] -> [96], relu ----------------
    const f16* wmid[2] = { wf2, wf3 };
    const float* bmid[2] = { b2, b3 };
#pragma unroll 1
    for (int L = 0; L < 2; ++L) {
        const f16* w = wmid[L];
        const float* bb = bmid[L];
        f16x8 a[18];
#pragma unroll
        for (int t = 0; t < 6; ++t)
#pragma unroll
            for (int kb = 0; kb < 3; ++kb)
                a[t * 3 + kb] = *(const f16x8*)(w + (t * 16 + n) * S2 + kb * 32 + 8 * q);
        f32x4 bias[6];
#pragma unroll
        for (int t = 0; t < 6; ++t)
            bias[t] = *(const f32x4*)(bb + t * 16 + 4 * q);
#pragma unroll
        for (int g = 0; g < G; ++g) {
            f16x8 bf[3];
#pragma unroll
            for (int kb = 0; kb < 3; ++kb)
                bf[kb] = *(const f16x8*)(&act[wave][g][n][kb * 32 + 8 * q]);
            f32x4 c[6];
#pragma unroll
            for (int t = 0; t < 6; ++t) {
                c[t] = bias[t];
#pragma unroll
                for (int kb = 0; kb < 3; ++kb)
                    c[t] = __builtin_amdgcn_mfma_f32_16x16x32_f16(a[t * 3 + kb], bf[kb], c[t], 0, 0, 0);
            }
#pragma unroll
            for (int t = 0; t < 6; ++t)
                store_relu4(&act[wave][g][n][t * 16 + 4 * q], c[t]);
        }
    }

    // ---------------- layer 4: [96] -> [11], scatter-add ----------------
    {
        f16x8 a[3];
#pragma unroll
        for (int kb = 0; kb < 3; ++kb)
            a[kb] = *(const f16x8*)(wf4 + n * S2 + kb * 32 + 8 * q);
        float bias[4];
#pragma unroll
        for (int r = 0; r < 4; ++r) {
            const int m = 4 * q + r;
            bias[r] = (m < 11) ? b4[m] : 0.0f;
        }
#pragma unroll
        for (int g = 0; g < G; ++g) {
            f16x8 bf[3];
#pragma unroll
            for (int kb = 0; kb < 3; ++kb)
                bf[kb] = *(const f16x8*)(&act[wave][g][n][kb * 32 + 8 * q]);
            f32x4 c = { bias[0], bias[1], bias[2], bias[3] };
#pragma unroll
            for (int kb = 0; kb < 3; ++kb)
                c = __builtin_amdgcn_mfma_f32_16x16x32_f16(a[kb], bf[kb], c, 0, 0, 0);
            const int eg = ebase + g * 16 + n;
            const bool valid = eg < E;
            const int e = valid ? eg : 0;
            const int d = dst[e];
            float* ag = agg + (size_t)d * EF;
#pragma unroll
            for (int r = 0; r < 4; ++r) {
                const int m = 4 * q + r;
                if (valid && m < 11) atomicAdd(&ag[m], c[r]);
            }
        }
    }
}

// ---------------- GRU + logits per node (f32, unchanged) ----------------
__global__ __launch_bounds__(256) void gru_node_kernel(
    const float* __restrict__ node_inputs,
    float* __restrict__ h, float* __restrict__ agg,
    const float* __restrict__ wih, const float* __restrict__ whh,
    const float* __restrict__ bih, const float* __restrict__ bhh,
    const float* __restrict__ fw, const float* __restrict__ fb,
    float* __restrict__ out_t, int N)
{
    const int n = blockIdx.x * blockDim.x + threadIdx.x;
    if (n >= N) return;

    float x[GIN];
#pragma unroll
    for (int k = 0; k < EF; ++k) {
        x[k] = agg[(size_t)n * EF + k];
        agg[(size_t)n * EF + k] = 0.0f;   // re-zero for next iteration's atomics
    }
#pragma unroll
    for (int k = 0; k < NIN; ++k) x[EF + k] = node_inputs[(size_t)n * NIN + k];

    float hv[HF];
#pragma unroll
    for (int k = 0; k < HF; ++k) hv[k] = h[(size_t)n * HF + k];

    float gi[3 * HF];
    float gh[3 * HF];
#pragma unroll
    for (int j = 0; j < 3 * HF; ++j) {
        float a = bih[j];
#pragma unroll
        for (int k = 0; k < GIN; ++k) a = fmaf(x[k], wih[j * GIN + k], a);
        gi[j] = a;
        float g = bhh[j];
#pragma unroll
        for (int k = 0; k < HF; ++k) g = fmaf(hv[k], whh[j * HF + k], g);
        gh[j] = g;
    }

    float hn[HF];
#pragma unroll
    for (int k = 0; k < HF; ++k) {
        const float r = 1.0f / (1.0f + __expf(-(gi[k] + gh[k])));
        const float z = 1.0f / (1.0f + __expf(-(gi[HF + k] + gh[HF + k])));
        const float nn = tanhf(gi[2 * HF + k] + r * gh[2 * HF + k]);
        hn[k] = (1.0f - z) * nn + z * hv[k];
    }
#pragma unroll
    for (int k = 0; k < HF; ++k) h[(size_t)n * HF + k] = hn[k];

    float l0 = fb[0], l1 = fb[1];
#pragma unroll
    for (int k = 0; k < HF; ++k) {
        l0 = fmaf(hn[k], fw[k], l0);
        l1 = fmaf(hn[k], fw[HF + k], l1);
    }
    out_t[(size_t)n * 2 + 0] = l0;
    out_t[(size_t)n * 2 + 1] = l1;
}

extern "C" void kernel_launch(void* const* d_in, const int* in_sizes, int n_in,
                              void* d_out, int out_size, void* d_ws, size_t ws_size,
                              hipStream_t stream) {
    const float* node_inputs = (const float*)d_in[0];
    const float* edge_attr   = (const float*)d_in[1];
    const float* W1 = (const float*)d_in[2];
    const float* b1 = (const float*)d_in[3];
    const float* W2 = (const float*)d_in[4];
    const float* b2 = (const float*)d_in[5];
    const float* W3 = (const float*)d_in[6];
    const float* b3 = (const float*)d_in[7];
    const float* W4 = (const float*)d_in[8];
    const float* b4 = (const float*)d_in[9];
    const float* gru_wih = (const float*)d_in[10];
    const float* gru_whh = (const float*)d_in[11];
    const float* gru_bih = (const float*)d_in[12];
    const float* gru_bhh = (const float*)d_in[13];
    const float* fin_w   = (const float*)d_in[14];
    const float* fin_b   = (const float*)d_in[15];
    const int* src_ids = (const int*)d_in[16];
    const int* dst_ids = (const int*)d_in[17];

    const int N = in_sizes[0] / NIN;   // 20000
    const int E = in_sizes[1] / EF;    // 320000

    float* h   = (float*)d_ws;                 // N*HF f32
    float* agg = h + (size_t)N * HF;           // N*EF f32
    f16*   wf  = (f16*)(agg + (size_t)N * EF); // preconverted f16 weights

    // zero h0 and agg; gru_node_kernel re-zeros agg each iteration
    hipMemsetAsync(d_ws, 0, (size_t)N * (HF + EF) * sizeof(float), stream);
    convert_weights<<<60, 256, 0, stream>>>(W1, W2, W3, W4, wf);

    float* out = (float*)d_out;
    const int edge_blocks = (E + 255) / 256;   // 256 edges per block
    const int node_blocks = (N + 255) / 256;

    for (int t = 0; t < N_ITERS; ++t) {
        edge_mlp_mfma<<<edge_blocks, 256, 0, stream>>>(
            h, edge_attr, wf, b1, b2, b3, b4, src_ids, dst_ids, agg, E);
        gru_node_kernel<<<node_blocks, 256, 0, stream>>>(
            node_inputs, h, agg, gru_wih, gru_whh, gru_bih, gru_bhh,
            fin_w, fin_b, out + (size_t)t * N * 2, N);
    }
}

// Round 3
// 604.712 us; speedup vs baseline: 4.9707x; 1.5862x over previous
//
#include <hip/hip_runtime.h>
#include <math.h>
#include <stdint.h>

typedef _Float16 f16;
typedef f16 f16x8 __attribute__((ext_vector_type(8)));
typedef f16 f16x4 __attribute__((ext_vector_type(4)));
typedef float f32x4 __attribute__((ext_vector_type(4)));

#define N_ITERS 7
#define HF 10      // GRU hidden size
#define NIN 9      // node inputs
#define EF 11      // edge features / message size
#define GIN (EF + NIN)

#define S1 40      // f16 row stride for W1 (K=32 padded)
#define S2 104     // f16 row stride for W2/W3/W4 + act LDS (208B = 13*16B, 16B-aligned rows)
#define G  4       // 16-edge groups per wave
#define MSTR 12    // msg row stride in f32 (11 + 1 pad, 48B)

union FragU { f16x8 v; uint32_t u[4]; uint2 p2[2]; uint4 q4; };

// ---------------- weight preconversion (once per launch) ----------------
__global__ __launch_bounds__(256) void convert_weights(
    const float* __restrict__ W1, const float* __restrict__ W2,
    const float* __restrict__ W3, const float* __restrict__ W4,
    f16* __restrict__ wf)
{
    f16* wf1 = wf;
    f16* wf2 = wf1 + 96 * S1;
    f16* wf3 = wf2 + 96 * S2;
    f16* wf4 = wf3 + 96 * S2;
    const int tid = blockIdx.x * 256 + threadIdx.x;
    const int nt = gridDim.x * 256;
    for (int i = tid; i < 96 * S1; i += nt) {
        int m = i / S1, k = i % S1;
        wf1[i] = (k < 31) ? (f16)W1[m * 31 + k] : (f16)0.f;
    }
    for (int i = tid; i < 96 * S2; i += nt) {
        int m = i / S2, k = i % S2;
        wf2[i] = (k < 96) ? (f16)W2[m * 96 + k] : (f16)0.f;
        wf3[i] = (k < 96) ? (f16)W3[m * 96 + k] : (f16)0.f;
    }
    for (int i = tid; i < 16 * S2; i += nt) {
        int m = i / S2, k = i % S2;
        wf4[i] = (m < 11 && k < 96) ? (f16)W4[m * 96 + k] : (f16)0.f;
    }
}

// ---------------- CSR construction (dst_ids is launch-invariant) ----------
__global__ __launch_bounds__(256) void count_edges(
    const int* __restrict__ dst, int* __restrict__ cnt, int E)
{
    int e = blockIdx.x * 256 + threadIdx.x;
    if (e < E) atomicAdd(&cnt[dst[e]], 1);
}

// single-block exclusive scan over cnt[0..N) -> row_ptr[0..N], nxt = copy
__global__ __launch_bounds__(1024) void scan_counts(
    const int* __restrict__ cnt, int* __restrict__ row_ptr,
    int* __restrict__ nxt, int N, int E)
{
    __shared__ int sums[1024];
    const int tid = threadIdx.x;
    const int C = (N + 1023) >> 10;
    const int base = tid * C;
    int local = 0;
    for (int i = 0; i < C; ++i) {
        int idx = base + i;
        if (idx < N) local += cnt[idx];
    }
    sums[tid] = local;
    __syncthreads();
    for (int off = 1; off < 1024; off <<= 1) {
        int v = (tid >= off) ? sums[tid - off] : 0;
        __syncthreads();
        sums[tid] += v;
        __syncthreads();
    }
    int run = sums[tid] - local;   // exclusive prefix of this chunk
    for (int i = 0; i < C; ++i) {
        int idx = base + i;
        if (idx < N) {
            row_ptr[idx] = run;
            nxt[idx] = run;
            run += cnt[idx];
        }
    }
    if (tid == 0) row_ptr[N] = E;
}

__global__ __launch_bounds__(256) void scatter_edges(
    const int* __restrict__ dst, int* __restrict__ nxt,
    int* __restrict__ perm, int E)
{
    int e = blockIdx.x * 256 + threadIdx.x;
    if (e < E) {
        int pos = atomicAdd(&nxt[dst[e]], 1);
        perm[pos] = e;
    }
}

// gather src/dst/edge_attr into dst-sorted order; ea packed as f16 fragments
__global__ __launch_bounds__(256) void pack_edges(
    const int* __restrict__ perm, const int* __restrict__ src,
    const int* __restrict__ dst, const float* __restrict__ ea,
    int* __restrict__ srcs, int* __restrict__ dsts,
    f16* __restrict__ eaA, f16* __restrict__ eaB, int E)
{
    int i = blockIdx.x * 256 + threadIdx.x;
    if (i >= E) return;
    int e = perm[i];
    srcs[i] = src[e];
    dsts[i] = dst[e];
    const float* r = ea + (size_t)e * EF;
    f16x4 a;
#pragma unroll
    for (int j = 0; j < 4; ++j) a[j] = (f16)r[j];
    *(f16x4*)(eaA + (size_t)i * 4) = a;
    f16x8 b;
#pragma unroll
    for (int j = 0; j < 7; ++j) b[j] = (f16)r[4 + j];
    b[7] = (f16)0.f;
    *(f16x8*)(eaB + (size_t)i * 8) = b;
}

// relu + cvt to f16x4 + 8B LDS store
__device__ __forceinline__ void store_relu4(f16* p, f32x4 c) {
    f16x4 o;
#pragma unroll
    for (int r = 0; r < 4; ++r) o[r] = (f16)fmaxf(c[r], 0.0f);
    *(f16x4*)p = o;
}

// ---------------- edge MLP via MFMA, dst-sorted, no atomics ----------------
__global__ __launch_bounds__(256, 2) void edge_mlp_mfma(
    const f16* __restrict__ h16, const f16* __restrict__ wf,
    const float* __restrict__ b1, const float* __restrict__ b2,
    const float* __restrict__ b3, const float* __restrict__ b4,
    const int* __restrict__ srcs, const int* __restrict__ dsts,
    const f16* __restrict__ eaA, const f16* __restrict__ eaB,
    float* __restrict__ msg, int E)
{
    const f16* wf1 = wf;
    const f16* wf2 = wf1 + 96 * S1;
    const f16* wf3 = wf2 + 96 * S2;
    const f16* wf4 = wf3 + 96 * S2;

    __shared__ f16 act[4][G][16][S2];   // 53,248 B

    const int wave = threadIdx.x >> 6;
    const int lane = threadIdx.x & 63;
    const int n = lane & 15;       // edge-in-group (B col / C col)
    const int q = lane >> 4;       // quad

    const int i0 = blockIdx.x * 256 + wave * (G * 16);

    const uint4* h16q = (const uint4*)h16;        // node = 2 uint4 (32B)
    const uint32_t* h16u = (const uint32_t*)h16;  // node = 8 dwords
    const uint2* eaAp = (const uint2*)eaA;
    const uint4* eaBp = (const uint4*)eaB;

    // ---------------- layer 1: [31] -> [96], relu ----------------
    {
        f16x8 a[6];
#pragma unroll
        for (int t = 0; t < 6; ++t)
            a[t] = *(const f16x8*)(wf1 + (t * 16 + n) * S1 + 8 * q);
        f32x4 bias[6];
#pragma unroll
        for (int t = 0; t < 6; ++t)
            bias[t] = *(const f32x4*)(b1 + t * 16 + 4 * q);
#pragma unroll
        for (int g = 0; g < G; ++g) {
            const int ig = i0 + g * 16 + n;
            const int ii = (ig < E) ? ig : 0;
            FragU bf;
            if (q == 0) {
                const int s = srcs[ii];
                bf.q4 = h16q[(size_t)s * 2];                  // h_s[0..7]
            } else if (q == 1) {
                const int s = srcs[ii];
                const int d = dsts[ii];
                bf.u[0] = h16u[(size_t)s * 8 + 4];            // h_s[8,9]
                uint2 t2 = *(const uint2*)(h16u + (size_t)d * 8);
                bf.u[1] = t2.x; bf.u[2] = t2.y;               // h_d[0..3]
                bf.u[3] = h16u[(size_t)d * 8 + 2];            // h_d[4,5]
            } else if (q == 2) {
                const int d = dsts[ii];
                bf.u[0] = h16u[(size_t)d * 8 + 3];            // h_d[6,7]
                bf.u[1] = h16u[(size_t)d * 8 + 4];            // h_d[8,9]
                uint2 t2 = eaAp[ii];
                bf.u[2] = t2.x; bf.u[3] = t2.y;               // ea[0..3]
            } else {
                bf.q4 = eaBp[ii];                             // ea[4..10],0
            }
#pragma unroll
            for (int t = 0; t < 6; ++t) {
                f32x4 c = __builtin_amdgcn_mfma_f32_16x16x32_f16(a[t], bf.v, bias[t], 0, 0, 0);
                store_relu4(&act[wave][g][n][t * 16 + 4 * q], c);
            }
        }
    }

    // ---------------- layers 2,3: [96] -> [96], relu ----------------
    const f16* wmid[2] = { wf2, wf3 };
    const float* bmid[2] = { b2, b3 };
#pragma unroll 1
    for (int L = 0; L < 2; ++L) {
        const f16* w = wmid[L];
        const float* bb = bmid[L];
        f16x8 a[18];
#pragma unroll
        for (int t = 0; t < 6; ++t)
#pragma unroll
            for (int kb = 0; kb < 3; ++kb)
                a[t * 3 + kb] = *(const f16x8*)(w + (t * 16 + n) * S2 + kb * 32 + 8 * q);
        f32x4 bias[6];
#pragma unroll
        for (int t = 0; t < 6; ++t)
            bias[t] = *(const f32x4*)(bb + t * 16 + 4 * q);
#pragma unroll
        for (int g = 0; g < G; ++g) {
            f16x8 bf[3];
#pragma unroll
            for (int kb = 0; kb < 3; ++kb)
                bf[kb] = *(const f16x8*)(&act[wave][g][n][kb * 32 + 8 * q]);
            f32x4 c[6];
#pragma unroll
            for (int t = 0; t < 6; ++t) {
                c[t] = bias[t];
#pragma unroll
                for (int kb = 0; kb < 3; ++kb)
                    c[t] = __builtin_amdgcn_mfma_f32_16x16x32_f16(a[t * 3 + kb], bf[kb], c[t], 0, 0, 0);
            }
#pragma unroll
            for (int t = 0; t < 6; ++t)
                store_relu4(&act[wave][g][n][t * 16 + 4 * q], c[t]);
        }
    }

    // ---------------- layer 4: [96] -> [11(+pad)], coalesced msg write ------
    {
        f16x8 a[3];
#pragma unroll
        for (int kb = 0; kb < 3; ++kb)
            a[kb] = *(const f16x8*)(wf4 + n * S2 + kb * 32 + 8 * q);
        float bias[4];
#pragma unroll
        for (int r = 0; r < 4; ++r) {
            const int m = 4 * q + r;
            bias[r] = (m < 11) ? b4[m] : 0.0f;
        }
#pragma unroll
        for (int g = 0; g < G; ++g) {
            f16x8 bf[3];
#pragma unroll
            for (int kb = 0; kb < 3; ++kb)
                bf[kb] = *(const f16x8*)(&act[wave][g][n][kb * 32 + 8 * q]);
            f32x4 c = { bias[0], bias[1], bias[2], bias[3] };
#pragma unroll
            for (int kb = 0; kb < 3; ++kb)
                c = __builtin_amdgcn_mfma_f32_16x16x32_f16(a[kb], bf[kb], c, 0, 0, 0);
            const int ig = i0 + g * 16 + n;
            if (q < 3 && ig < E)   // rows m=0..11; m=11 is exact 0 (zero-padded W4/b4)
                *(f32x4*)(msg + (size_t)ig * MSTR + 4 * q) = c;
        }
    }
}

// ---------------- GRU + CSR aggregation + logits per node ----------------
__global__ __launch_bounds__(256) void gru_node_kernel(
    const float* __restrict__ node_inputs,
    float* __restrict__ h, f16* __restrict__ h16,
    const int* __restrict__ row_ptr, const float* __restrict__ msg,
    const float* __restrict__ wih, const float* __restrict__ whh,
    const float* __restrict__ bih, const float* __restrict__ bhh,
    const float* __restrict__ fw, const float* __restrict__ fb,
    float* __restrict__ out_t, int N)
{
    const int n = blockIdx.x * blockDim.x + threadIdx.x;
    if (n >= N) return;

    float x[GIN];
#pragma unroll
    for (int k = 0; k < EF; ++k) x[k] = 0.0f;
    const int r0 = row_ptr[n], r1 = row_ptr[n + 1];
    for (int r = r0; r < r1; ++r) {
        const f32x4* mp = (const f32x4*)(msg + (size_t)r * MSTR);
        f32x4 a = mp[0], b = mp[1], c = mp[2];
        x[0] += a[0]; x[1] += a[1]; x[2] += a[2]; x[3] += a[3];
        x[4] += b[0]; x[5] += b[1]; x[6] += b[2]; x[7] += b[3];
        x[8] += c[0]; x[9] += c[1]; x[10] += c[2];
    }
#pragma unroll
    for (int k = 0; k < NIN; ++k) x[EF + k] = node_inputs[(size_t)n * NIN + k];

    float hv[HF];
#pragma unroll
    for (int k = 0; k < HF; ++k) hv[k] = h[(size_t)n * HF + k];

    float gi[3 * HF];
    float gh[3 * HF];
#pragma unroll
    for (int j = 0; j < 3 * HF; ++j) {
        float a = bih[j];
#pragma unroll
        for (int k = 0; k < GIN; ++k) a = fmaf(x[k], wih[j * GIN + k], a);
        gi[j] = a;
        float g = bhh[j];
#pragma unroll
        for (int k = 0; k < HF; ++k) g = fmaf(hv[k], whh[j * HF + k], g);
        gh[j] = g;
    }

    float hn[HF];
#pragma unroll
    for (int k = 0; k < HF; ++k) {
        const float r = 1.0f / (1.0f + __expf(-(gi[k] + gh[k])));
        const float z = 1.0f / (1.0f + __expf(-(gi[HF + k] + gh[HF + k])));
        const float nn = tanhf(gi[2 * HF + k] + r * gh[2 * HF + k]);
        hn[k] = (1.0f - z) * nn + z * hv[k];
    }
#pragma unroll
    for (int k = 0; k < HF; ++k) {
        h[(size_t)n * HF + k] = hn[k];
        h16[(size_t)n * 16 + k] = (f16)hn[k];
    }

    float l0 = fb[0], l1 = fb[1];
#pragma unroll
    for (int k = 0; k < HF; ++k) {
        l0 = fmaf(hn[k], fw[k], l0);
        l1 = fmaf(hn[k], fw[HF + k], l1);
    }
    out_t[(size_t)n * 2 + 0] = l0;
    out_t[(size_t)n * 2 + 1] = l1;
}

extern "C" void kernel_launch(void* const* d_in, const int* in_sizes, int n_in,
                              void* d_out, int out_size, void* d_ws, size_t ws_size,
                              hipStream_t stream) {
    const float* node_inputs = (const float*)d_in[0];
    const float* edge_attr   = (const float*)d_in[1];
    const float* W1 = (const float*)d_in[2];
    const float* b1 = (const float*)d_in[3];
    const float* W2 = (const float*)d_in[4];
    const float* b2 = (const float*)d_in[5];
    const float* W3 = (const float*)d_in[6];
    const float* b3 = (const float*)d_in[7];
    const float* W4 = (const float*)d_in[8];
    const float* b4 = (const float*)d_in[9];
    const float* gru_wih = (const float*)d_in[10];
    const float* gru_whh = (const float*)d_in[11];
    const float* gru_bih = (const float*)d_in[12];
    const float* gru_bhh = (const float*)d_in[13];
    const float* fin_w   = (const float*)d_in[14];
    const float* fin_b   = (const float*)d_in[15];
    const int* src_ids = (const int*)d_in[16];
    const int* dst_ids = (const int*)d_in[17];

    const int N = in_sizes[0] / NIN;   // 20000
    const int E = in_sizes[1] / EF;    // 320000

    // ---- workspace carve-up (256B-aligned chunks) ----
    char* base = (char*)d_ws;
    size_t off = 0;
    auto alloc = [&](size_t bytes) -> char* {
        char* p = base + off;
        off += (bytes + 255) & ~(size_t)255;
        return p;
    };
    float* msg    = (float*)alloc((size_t)E * MSTR * 4);  // 15.4 MB
    f16*   eaB    = (f16*)  alloc((size_t)E * 8 * 2);
    f16*   eaA    = (f16*)  alloc((size_t)E * 4 * 2);
    f16*   h16    = (f16*)  alloc((size_t)N * 16 * 2);
    float* hbuf   = (float*)alloc((size_t)N * HF * 4);
    f16*   wf     = (f16*)  alloc(52000 * 2);
    int*   row_ptr= (int*)  alloc((size_t)(N + 1) * 4);
    int*   cnt    = (int*)  alloc((size_t)N * 4);
    int*   nxt    = (int*)  alloc((size_t)N * 4);
    int*   perm   = (int*)  alloc((size_t)E * 4);
    int*   srcs   = (int*)  alloc((size_t)E * 4);
    int*   dsts   = (int*)  alloc((size_t)E * 4);

    const int eb = (E + 255) / 256;
    const int nb = (N + 255) / 256;

    // ---- per-launch setup (d_ws is re-poisoned before every call) ----
    hipMemsetAsync(h16, 0, (size_t)N * 16 * 2, stream);
    hipMemsetAsync(hbuf, 0, (size_t)N * HF * 4, stream);
    hipMemsetAsync(cnt, 0, (size_t)N * 4, stream);
    convert_weights<<<60, 256, 0, stream>>>(W1, W2, W3, W4, wf);
    count_edges<<<eb, 256, 0, stream>>>(dst_ids, cnt, E);
    scan_counts<<<1, 1024, 0, stream>>>(cnt, row_ptr, nxt, N, E);
    scatter_edges<<<eb, 256, 0, stream>>>(dst_ids, nxt, perm, E);
    pack_edges<<<eb, 256, 0, stream>>>(perm, src_ids, dst_ids, edge_attr,
                                       srcs, dsts, eaA, eaB, E);

    float* out = (float*)d_out;
    for (int t = 0; t < N_ITERS; ++t) {
        edge_mlp_mfma<<<eb, 256, 0, stream>>>(
            h16, wf, b1, b2, b3, b4, srcs, dsts, eaA, eaB, msg, E);
        gru_node_kernel<<<nb, 256, 0, stream>>>(
            node_inputs, hbuf, h16, row_ptr, msg,
            gru_wih, gru_whh, gru_bih, gru_bhh,
            fin_w, fin_b, out + (size_t)t * N * 2, N);
    }
}